// Round 5
// baseline (811.793 us; speedup 1.0000x reference)
//
#include <hip/hip_runtime.h>
#include <cstdint>
#include <cstddef>

// Graph U-Net (no pooling), N=8192, D=256, L=3.
// R5: XCD-pinned SpMM. Grid (8 chunks, GN/4): linear block id = chunk + 8*row
// => id%8 = chunk => each XCD gathers only its 64B column slice of hs
// (512 KB footprint, trivially L2-resident; one L3 cold fill then local hits).
// Wave = 4 neighbor-groups x 16 lanes x 1 dword (2 bf16); unroll-8 per group.
// Neighbor lists padded to %4 with self-index (compensated in epilogue).
// GEMM stays MFMA bf16 16x16x32 direct-from-global (R4).

#define GN 8192
#define GD 256
#define CAP 320   // max degree capacity; max observed degree ~175

typedef unsigned int uint32;
using frag_ab = __attribute__((ext_vector_type(8))) short;   // 8 bf16
using frag_cd = __attribute__((ext_vector_type(4))) float;   // 4 fp32

// RNE float -> bf16 bits (values finite)
static __device__ inline unsigned short f2bf(float x) {
    uint32 u = __float_as_uint(x);
    u += 0x7fffu + ((u >> 16) & 1u);
    return (unsigned short)(u >> 16);
}

// ---------------------------------------------------------------------------
// Kernel 1: build adjacency lists + dinv. One block per row.
// Pads col list with self-index i to a multiple of 4 (SpMM compensates).
__global__ __launch_bounds__(256) void k_build(const float* __restrict__ g,
                                               unsigned short* __restrict__ col,
                                               int* __restrict__ cnt,
                                               float* __restrict__ dinv)
{
    __shared__ int s_cnt;
    const int i = blockIdx.x;
    const int tid = threadIdx.x;
    if (tid == 0) s_cnt = 0;
    __syncthreads();
    const float4* grow = (const float4*)(g + (size_t)i * GN);
    unsigned short* crow = col + (size_t)i * CAP;
    for (int j4 = tid; j4 < GN / 4; j4 += 256) {
        float4 v = grow[j4];
        int j = j4 * 4;
        if (v.x != 0.0f) { int p = atomicAdd(&s_cnt, 1); if (p < CAP) crow[p] = (unsigned short)(j + 0); }
        if (v.y != 0.0f) { int p = atomicAdd(&s_cnt, 1); if (p < CAP) crow[p] = (unsigned short)(j + 1); }
        if (v.z != 0.0f) { int p = atomicAdd(&s_cnt, 1); if (p < CAP) crow[p] = (unsigned short)(j + 2); }
        if (v.w != 0.0f) { int p = atomicAdd(&s_cnt, 1); if (p < CAP) crow[p] = (unsigned short)(j + 3); }
    }
    __syncthreads();
    if (tid == 0) {
        int n = s_cnt; if (n > CAP) n = CAP;
        cnt[i] = n;
        dinv[i] = rsqrtf((float)s_cnt + 1.0f);
        int pad = (4 - (n & 3)) & 3;            // pad to multiple of 4 (<= CAP after pad
        for (int k = 0; k < pad; ++k)           //  since CAP%4==0 and n<=CAP)
            if (n + k < CAP) crow[n + k] = (unsigned short)i;
    }
}

// ---------------------------------------------------------------------------
// Kernel 2: hs_bf = bf16(dinv[:,None] * h)
__global__ __launch_bounds__(256) void k_scale(const float* __restrict__ h,
                                               const float* __restrict__ dinv,
                                               unsigned short* __restrict__ hs_bf)
{
    int idx = blockIdx.x * 256 + threadIdx.x;      // float4 index
    float4 v = ((const float4*)h)[idx];
    int row = idx / (GD / 4);
    float dv = dinv[row];
    ushort4 r;
    r.x = f2bf(v.x * dv); r.y = f2bf(v.y * dv);
    r.z = f2bf(v.z * dv); r.w = f2bf(v.w * dv);
    ((ushort4*)hs_bf)[idx] = r;
}

// ---------------------------------------------------------------------------
// Kernel 2b: generic fp32 -> bf16 convert (weights)
__global__ __launch_bounds__(256) void k_f2bf(const float* __restrict__ src,
                                              unsigned short* __restrict__ dst)
{
    int idx = blockIdx.x * 256 + threadIdx.x;      // float4 index
    float4 v = ((const float4*)src)[idx];
    ushort4 r;
    r.x = f2bf(v.x); r.y = f2bf(v.y); r.z = f2bf(v.z); r.w = f2bf(v.w);
    ((ushort4*)dst)[idx] = r;
}

// ---------------------------------------------------------------------------
// Kernel 3: XCD-pinned SpMM. Grid (8, GN/4); blockIdx.x = 64B column chunk.
// 4 rows/block (one wave each). Lane = j*16+q: group j gathers neighbor
// sc[t+j]'s 64B chunk (16 dwords). One load inst = 4 neighbors x 64B.
// Cross-group combine via shfl_xor(16,32); group 0 adds (1-pads)*self,
// scales, writes 64B.
__global__ __launch_bounds__(256) void k_spmm(const uint32* __restrict__ hsw,
                                              const unsigned short* __restrict__ col,
                                              const int* __restrict__ cnt,
                                              const float* __restrict__ dinv,
                                              uint32* __restrict__ yw)
{
    __shared__ unsigned short s_cols[4][CAP];
    const int tid  = threadIdx.x;
    const int lr   = tid >> 6;         // wave id = local row 0..3
    const int lane = tid & 63;
    const int j    = lane >> 4;        // neighbor group 0..3
    const int q    = lane & 15;        // dword within 64B chunk
    const int i     = blockIdx.y * 4 + lr;
    const int cbase = blockIdx.x * 16 + q;   // dword col (row stride 128)
    const int n  = cnt[i];
    const int n4 = (n + 3) & ~3;
    unsigned short* sc = s_cols[lr];
    for (int t = lane; t < n4; t += 64) sc[t] = col[(size_t)i * CAP + t];
    // wave-coherent staging: producer == consumer wave; no barrier.

    float alo = 0.f, ahi = 0.f;
    int t = j;
    for (; t + 28 < n4; t += 32) {     // 8 neighbors per group per iter
        int c0 = sc[t], c1 = sc[t + 4], c2 = sc[t + 8],  c3 = sc[t + 12];
        int c4 = sc[t + 16], c5 = sc[t + 20], c6 = sc[t + 24], c7 = sc[t + 28];
        uint32 u0 = hsw[(size_t)c0 * 128 + cbase];
        uint32 u1 = hsw[(size_t)c1 * 128 + cbase];
        uint32 u2 = hsw[(size_t)c2 * 128 + cbase];
        uint32 u3 = hsw[(size_t)c3 * 128 + cbase];
        uint32 u4 = hsw[(size_t)c4 * 128 + cbase];
        uint32 u5 = hsw[(size_t)c5 * 128 + cbase];
        uint32 u6 = hsw[(size_t)c6 * 128 + cbase];
        uint32 u7 = hsw[(size_t)c7 * 128 + cbase];
        alo += __uint_as_float(u0 << 16); ahi += __uint_as_float(u0 & 0xffff0000u);
        alo += __uint_as_float(u1 << 16); ahi += __uint_as_float(u1 & 0xffff0000u);
        alo += __uint_as_float(u2 << 16); ahi += __uint_as_float(u2 & 0xffff0000u);
        alo += __uint_as_float(u3 << 16); ahi += __uint_as_float(u3 & 0xffff0000u);
        alo += __uint_as_float(u4 << 16); ahi += __uint_as_float(u4 & 0xffff0000u);
        alo += __uint_as_float(u5 << 16); ahi += __uint_as_float(u5 & 0xffff0000u);
        alo += __uint_as_float(u6 << 16); ahi += __uint_as_float(u6 & 0xffff0000u);
        alo += __uint_as_float(u7 << 16); ahi += __uint_as_float(u7 & 0xffff0000u);
    }
    for (; t < n4; t += 4) {
        uint32 u = hsw[(size_t)sc[t] * 128 + cbase];
        alo += __uint_as_float(u << 16); ahi += __uint_as_float(u & 0xffff0000u);
    }

    alo += __shfl_xor(alo, 16, 64); ahi += __shfl_xor(ahi, 16, 64);
    alo += __shfl_xor(alo, 32, 64); ahi += __shfl_xor(ahi, 32, 64);

    if (j == 0) {
        uint32 us = hsw[(size_t)i * 128 + cbase];      // self (+I), coeff-adjusted
        float slo = __uint_as_float(us << 16);
        float shi = __uint_as_float(us & 0xffff0000u);
        float coeff = (float)(1 - (n4 - n));           // 1 minus pad count
        alo += coeff * slo; ahi += coeff * shi;
        float dv = dinv[i];
        yw[(size_t)i * 128 + cbase] = (uint32)f2bf(alo * dv) | ((uint32)f2bf(ahi * dv) << 16);
    }
}

// ---------------------------------------------------------------------------
// Kernel 4: MFMA bf16 linear layer (R4). C = relu(Y @ W^T + b) + epilogues:
//   h_out (fp32), hs_out (bf16 = dinv*(v+skip)), sum_out (fp32 = v+add_src).
// Layouts (m89/m91-verified): A[m=lane&15][k=quad*8+j]; C/D row=quad*4+reg,
// col=lane&15.
__global__ __launch_bounds__(256) void k_gemm(const unsigned short* __restrict__ Y,
                                              const unsigned short* __restrict__ W,
                                              const float* __restrict__ bias,
                                              const float* __restrict__ dinv,
                                              const float* __restrict__ skip,
                                              float* __restrict__ h_out,
                                              unsigned short* __restrict__ hs_out,
                                              float* __restrict__ sum_out,
                                              const float* __restrict__ add_src)
{
    const int tid  = threadIdx.x;
    const int w    = tid >> 6;         // wave 0..3
    const int lane = tid & 63;
    const int quad = lane >> 4;
    const int l16  = lane & 15;
    const int m0 = blockIdx.x * 64 + w * 16;   // wave's 16 rows
    const int n0 = blockIdx.y * 64;            // block's 64 cols

    frag_cd acc0 = {0.f,0.f,0.f,0.f}, acc1 = {0.f,0.f,0.f,0.f};
    frag_cd acc2 = {0.f,0.f,0.f,0.f}, acc3 = {0.f,0.f,0.f,0.f};

    const size_t abase  = (size_t)(m0 + l16) * GD + quad * 8;
    const size_t bbase0 = (size_t)(n0 +  0 + l16) * GD + quad * 8;
    const size_t bbase1 = (size_t)(n0 + 16 + l16) * GD + quad * 8;
    const size_t bbase2 = (size_t)(n0 + 32 + l16) * GD + quad * 8;
    const size_t bbase3 = (size_t)(n0 + 48 + l16) * GD + quad * 8;

#pragma unroll
    for (int k0 = 0; k0 < GD; k0 += 32) {
        frag_ab a  = *(const frag_ab*)(Y + abase  + k0);
        frag_ab b0 = *(const frag_ab*)(W + bbase0 + k0);
        frag_ab b1 = *(const frag_ab*)(W + bbase1 + k0);
        frag_ab b2 = *(const frag_ab*)(W + bbase2 + k0);
        frag_ab b3 = *(const frag_ab*)(W + bbase3 + k0);
        acc0 = __builtin_amdgcn_mfma_f32_16x16x32_bf16(a, b0, acc0, 0, 0, 0);
        acc1 = __builtin_amdgcn_mfma_f32_16x16x32_bf16(a, b1, acc1, 0, 0, 0);
        acc2 = __builtin_amdgcn_mfma_f32_16x16x32_bf16(a, b2, acc2, 0, 0, 0);
        acc3 = __builtin_amdgcn_mfma_f32_16x16x32_bf16(a, b3, acc3, 0, 0, 0);
    }

    const float bn0 = bias[n0 +  0 + l16];
    const float bn1 = bias[n0 + 16 + l16];
    const float bn2 = bias[n0 + 32 + l16];
    const float bn3 = bias[n0 + 48 + l16];

#pragma unroll
    for (int reg = 0; reg < 4; ++reg) {
        const int m = m0 + quad * 4 + reg;
        const float dv = dinv[m];
        float v[4];
        v[0] = fmaxf(acc0[reg] + bn0, 0.f);
        v[1] = fmaxf(acc1[reg] + bn1, 0.f);
        v[2] = fmaxf(acc2[reg] + bn2, 0.f);
        v[3] = fmaxf(acc3[reg] + bn3, 0.f);
#pragma unroll
        for (int nt = 0; nt < 4; ++nt) {
            const size_t idx = (size_t)m * GD + n0 + nt * 16 + l16;
            const float x = v[nt];
            if (h_out)  h_out[idx] = x;
            if (hs_out) {
                float s = skip ? skip[idx] : 0.f;
                hs_out[idx] = f2bf(dv * (x + s));
            }
            if (sum_out) sum_out[idx] = x + add_src[idx];
        }
    }
}

// ---------------------------------------------------------------------------
extern "C" void kernel_launch(void* const* d_in, const int* in_sizes, int n_in,
                              void* d_out, int out_size, void* d_ws, size_t ws_size,
                              hipStream_t stream)
{
    const float* g  = (const float*)d_in[0];
    const float* h  = (const float*)d_in[1];
    const float* Wd = (const float*)d_in[2];
    const float* bd = (const float*)d_in[3];
    const float* Wb = (const float*)d_in[4];
    const float* bb = (const float*)d_in[5];
    const float* Wu = (const float*)d_in[6];
    const float* bu = (const float*)d_in[7];
    float* out = (float*)d_out;

    char* ws = (char*)d_ws;
    float*          dinv = (float*)ws;                               // 32 KB
    int*            cnt  = (int*)(ws + 32 * 1024);                   // 32 KB
    unsigned short* col  = (unsigned short*)(ws + 64 * 1024);        // 5.24 MB
    size_t off = 64 * 1024 + (size_t)GN * CAP * sizeof(unsigned short);
    off = (off + 255) & ~(size_t)255;
    unsigned short* hs_bf = (unsigned short*)(ws + off); off += (size_t)GN * GD * 2;  // 4 MB
    unsigned short* y_bf  = (unsigned short*)(ws + off); off += (size_t)GN * GD * 2;  // 4 MB
    unsigned short* w_bf  = (unsigned short*)(ws + off); off += (size_t)7 * GD * GD * 2; // 0.9 MB
    off = (off + 255) & ~(size_t)255;
    float* dbuf1 = (float*)(ws + off); off += (size_t)GN * GD * 4;   // 8 MB
    float* dbuf2 = (float*)(ws + off); off += (size_t)GN * GD * 4;   // 8 MB
    float* dbuf3 = (float*)(ws + off); off += (size_t)GN * GD * 4;   // 8 MB
    (void)ws_size; (void)in_sizes; (void)n_in; (void)out_size;

    const size_t ND = (size_t)GN * GD;
    const int WSZ = GD * GD;   // 65536 elements per weight matrix
    dim3 ggrid(GN / 64, GD / 64);
    dim3 sgrid(8, GN / 4);     // x = chunk (fast dim) => id%8 = chunk = XCD pin

    k_build<<<GN, 256, 0, stream>>>(g, col, cnt, dinv);
    k_scale<<<GN * GD / 4 / 256, 256, 0, stream>>>(h, dinv, hs_bf);
    k_f2bf<<<3 * WSZ / 4 / 256, 256, 0, stream>>>(Wd, w_bf + 0 * (size_t)WSZ);
    k_f2bf<<<1 * WSZ / 4 / 256, 256, 0, stream>>>(Wb, w_bf + 3 * (size_t)WSZ);
    k_f2bf<<<3 * WSZ / 4 / 256, 256, 0, stream>>>(Wu, w_bf + 4 * (size_t)WSZ);

    // down 0..2: h_out -> dbuf, hs_out -> hs_bf (no skip)
    k_spmm<<<sgrid, 256, 0, stream>>>((const uint32*)hs_bf, col, cnt, dinv, (uint32*)y_bf);
    k_gemm<<<ggrid, 256, 0, stream>>>(y_bf, w_bf + 0 * (size_t)WSZ, bd + 0 * GD, dinv, nullptr, dbuf1, hs_bf, nullptr, nullptr);
    k_spmm<<<sgrid, 256, 0, stream>>>((const uint32*)hs_bf, col, cnt, dinv, (uint32*)y_bf);
    k_gemm<<<ggrid, 256, 0, stream>>>(y_bf, w_bf + 1 * (size_t)WSZ, bd + 1 * GD, dinv, nullptr, dbuf2, hs_bf, nullptr, nullptr);
    k_spmm<<<sgrid, 256, 0, stream>>>((const uint32*)hs_bf, col, cnt, dinv, (uint32*)y_bf);
    k_gemm<<<ggrid, 256, 0, stream>>>(y_bf, w_bf + 2 * (size_t)WSZ, bd + 2 * GD, dinv, nullptr, dbuf3, hs_bf, nullptr, nullptr);

    // bottom: hs_out with skip = down_outs[2]
    k_spmm<<<sgrid, 256, 0, stream>>>((const uint32*)hs_bf, col, cnt, dinv, (uint32*)y_bf);
    k_gemm<<<ggrid, 256, 0, stream>>>(y_bf, w_bf + 3 * (size_t)WSZ, bb, dinv, dbuf3, nullptr, hs_bf, nullptr, nullptr);

    // up 0: out[0] = h5; next hs with skip = down_outs[1]
    k_spmm<<<sgrid, 256, 0, stream>>>((const uint32*)hs_bf, col, cnt, dinv, (uint32*)y_bf);
    k_gemm<<<ggrid, 256, 0, stream>>>(y_bf, w_bf + 4 * (size_t)WSZ, bu + 0 * GD, dinv, dbuf2, out + 0 * ND, hs_bf, nullptr, nullptr);
    // up 1: out[1] = h6; next hs with skip = down_outs[0]
    k_spmm<<<sgrid, 256, 0, stream>>>((const uint32*)hs_bf, col, cnt, dinv, (uint32*)y_bf);
    k_gemm<<<ggrid, 256, 0, stream>>>(y_bf, w_bf + 5 * (size_t)WSZ, bu + 1 * GD, dinv, dbuf1, out + 1 * ND, hs_bf, nullptr, nullptr);
    // up 2: out[2] = h7; out[3] = h7 + org_h
    k_spmm<<<sgrid, 256, 0, stream>>>((const uint32*)hs_bf, col, cnt, dinv, (uint32*)y_bf);
    k_gemm<<<ggrid, 256, 0, stream>>>(y_bf, w_bf + 6 * (size_t)WSZ, bu + 2 * GD, dinv, nullptr, out + 2 * ND, nullptr, out + 3 * ND, h);
}

// Round 6
// 785.293 us; speedup vs baseline: 1.0337x; 1.0337x over previous
//
#include <hip/hip_runtime.h>
#include <cstdint>
#include <cstddef>

// Graph U-Net (no pooling), N=8192, D=256, L=3.
// R6: SpMM = one wave per row, single pass (lane owns 8B => 512B bf16 row per
// gather inst). Neighbor indices via broadcast uint4 load + readfirstlane =>
// SGPR index stream, scalar-pipe unpack, no LDS, no per-neighbor VALU addr
// math. Lists padded to %8 with self-index (coeff-compensated).
// GEMM: MFMA bf16 16x16x32 direct-from-global (R4, best known).

#define GN 8192
#define GD 256
#define CAP 320   // max degree capacity; max observed degree ~175; %8 == 0

typedef unsigned int uint32;
using frag_ab = __attribute__((ext_vector_type(8))) short;   // 8 bf16
using frag_cd = __attribute__((ext_vector_type(4))) float;   // 4 fp32

// RNE float -> bf16 bits (values finite)
static __device__ inline unsigned short f2bf(float x) {
    uint32 u = __float_as_uint(x);
    u += 0x7fffu + ((u >> 16) & 1u);
    return (unsigned short)(u >> 16);
}

// ---------------------------------------------------------------------------
// Kernel 1: build adjacency lists + dinv. One block per row.
// Pads col list with self-index i to a multiple of 8 (SpMM compensates).
__global__ __launch_bounds__(256) void k_build(const float* __restrict__ g,
                                               unsigned short* __restrict__ col,
                                               int* __restrict__ cnt,
                                               float* __restrict__ dinv)
{
    __shared__ int s_cnt;
    const int i = blockIdx.x;
    const int tid = threadIdx.x;
    if (tid == 0) s_cnt = 0;
    __syncthreads();
    const float4* grow = (const float4*)(g + (size_t)i * GN);
    unsigned short* crow = col + (size_t)i * CAP;
    for (int j4 = tid; j4 < GN / 4; j4 += 256) {
        float4 v = grow[j4];
        int j = j4 * 4;
        if (v.x != 0.0f) { int p = atomicAdd(&s_cnt, 1); if (p < CAP) crow[p] = (unsigned short)(j + 0); }
        if (v.y != 0.0f) { int p = atomicAdd(&s_cnt, 1); if (p < CAP) crow[p] = (unsigned short)(j + 1); }
        if (v.z != 0.0f) { int p = atomicAdd(&s_cnt, 1); if (p < CAP) crow[p] = (unsigned short)(j + 2); }
        if (v.w != 0.0f) { int p = atomicAdd(&s_cnt, 1); if (p < CAP) crow[p] = (unsigned short)(j + 3); }
    }
    __syncthreads();
    if (tid == 0) {
        int n = s_cnt; if (n > CAP) n = CAP;
        cnt[i] = n;
        dinv[i] = rsqrtf((float)s_cnt + 1.0f);
        int n8 = (n + 7) & ~7;                    // pad to multiple of 8
        for (int k = n; k < n8; ++k)
            if (k < CAP) crow[k] = (unsigned short)i;
    }
}

// ---------------------------------------------------------------------------
// Kernel 2: hs_bf = bf16(dinv[:,None] * h)
__global__ __launch_bounds__(256) void k_scale(const float* __restrict__ h,
                                               const float* __restrict__ dinv,
                                               unsigned short* __restrict__ hs_bf)
{
    int idx = blockIdx.x * 256 + threadIdx.x;      // float4 index
    float4 v = ((const float4*)h)[idx];
    int row = idx / (GD / 4);
    float dv = dinv[row];
    ushort4 r;
    r.x = f2bf(v.x * dv); r.y = f2bf(v.y * dv);
    r.z = f2bf(v.z * dv); r.w = f2bf(v.w * dv);
    ((ushort4*)hs_bf)[idx] = r;
}

// ---------------------------------------------------------------------------
// Kernel 2b: generic fp32 -> bf16 convert (weights)
__global__ __launch_bounds__(256) void k_f2bf(const float* __restrict__ src,
                                              unsigned short* __restrict__ dst)
{
    int idx = blockIdx.x * 256 + threadIdx.x;      // float4 index
    float4 v = ((const float4*)src)[idx];
    ushort4 r;
    r.x = f2bf(v.x); r.y = f2bf(v.y); r.z = f2bf(v.z); r.w = f2bf(v.w);
    ((ushort4*)dst)[idx] = r;
}

// ---------------------------------------------------------------------------
// Kernel 3: SpMM, one wave per row, single pass, SGPR index stream.
// Lane owns uints [lane*2, lane*2+1] of the 128-uint (256 bf16) row.
// Per 8 neighbors: 1 broadcast uint4 index load (+readfirstlane -> SGPR),
// 8 dwordx2 gathers in flight, fp32 accumulate in 2 independent banks.
// y[i,:] = bf16(dinv[i]*(coeff*hs[i,:] + sum_padded hs[c,:])), coeff = 1-pads.
__global__ __launch_bounds__(256) void k_spmm(const uint32* __restrict__ hsw,
                                              const unsigned short* __restrict__ col,
                                              const int* __restrict__ cnt,
                                              const float* __restrict__ dinv,
                                              uint32* __restrict__ yw)
{
    const int tid  = threadIdx.x;
    const int lw   = tid >> 6;         // wave id = local row
    const int lane = tid & 63;
    const int i = blockIdx.x * 4 + lw;
    const int n = cnt[i];
    int n8 = (n + 7) & ~7; if (n8 > CAP) n8 = CAP;
    const uint4* idxp = (const uint4*)(col + (size_t)i * CAP);   // 8 idx / uint4
    const uint32* lbase = hsw + lane * 2;

    float a0=0.f,a1=0.f,a2=0.f,a3=0.f;     // bank A
    float b0=0.f,b1=0.f,b2=0.f,b3=0.f;     // bank B

    for (int t8 = 0; t8 < n8; t8 += 8) {
        uint4 packed = idxp[t8 >> 3];      // all lanes same addr -> broadcast
        uint32 p0 = (uint32)__builtin_amdgcn_readfirstlane((int)packed.x);
        uint32 p1 = (uint32)__builtin_amdgcn_readfirstlane((int)packed.y);
        uint32 p2 = (uint32)__builtin_amdgcn_readfirstlane((int)packed.z);
        uint32 p3 = (uint32)__builtin_amdgcn_readfirstlane((int)packed.w);
        const int c0 = (int)(p0 & 0xffffu), c1 = (int)(p0 >> 16);
        const int c2 = (int)(p1 & 0xffffu), c3 = (int)(p1 >> 16);
        const int c4 = (int)(p2 & 0xffffu), c5 = (int)(p2 >> 16);
        const int c6 = (int)(p3 & 0xffffu), c7 = (int)(p3 >> 16);
        uint2 u0 = *(const uint2*)(lbase + (size_t)c0 * 128);
        uint2 u1 = *(const uint2*)(lbase + (size_t)c1 * 128);
        uint2 u2 = *(const uint2*)(lbase + (size_t)c2 * 128);
        uint2 u3 = *(const uint2*)(lbase + (size_t)c3 * 128);
        uint2 u4 = *(const uint2*)(lbase + (size_t)c4 * 128);
        uint2 u5 = *(const uint2*)(lbase + (size_t)c5 * 128);
        uint2 u6 = *(const uint2*)(lbase + (size_t)c6 * 128);
        uint2 u7 = *(const uint2*)(lbase + (size_t)c7 * 128);
        a0 += __uint_as_float(u0.x << 16); a1 += __uint_as_float(u0.x & 0xffff0000u);
        a2 += __uint_as_float(u0.y << 16); a3 += __uint_as_float(u0.y & 0xffff0000u);
        b0 += __uint_as_float(u1.x << 16); b1 += __uint_as_float(u1.x & 0xffff0000u);
        b2 += __uint_as_float(u1.y << 16); b3 += __uint_as_float(u1.y & 0xffff0000u);
        a0 += __uint_as_float(u2.x << 16); a1 += __uint_as_float(u2.x & 0xffff0000u);
        a2 += __uint_as_float(u2.y << 16); a3 += __uint_as_float(u2.y & 0xffff0000u);
        b0 += __uint_as_float(u3.x << 16); b1 += __uint_as_float(u3.x & 0xffff0000u);
        b2 += __uint_as_float(u3.y << 16); b3 += __uint_as_float(u3.y & 0xffff0000u);
        a0 += __uint_as_float(u4.x << 16); a1 += __uint_as_float(u4.x & 0xffff0000u);
        a2 += __uint_as_float(u4.y << 16); a3 += __uint_as_float(u4.y & 0xffff0000u);
        b0 += __uint_as_float(u5.x << 16); b1 += __uint_as_float(u5.x & 0xffff0000u);
        b2 += __uint_as_float(u5.y << 16); b3 += __uint_as_float(u5.y & 0xffff0000u);
        a0 += __uint_as_float(u6.x << 16); a1 += __uint_as_float(u6.x & 0xffff0000u);
        a2 += __uint_as_float(u6.y << 16); a3 += __uint_as_float(u6.y & 0xffff0000u);
        b0 += __uint_as_float(u7.x << 16); b1 += __uint_as_float(u7.x & 0xffff0000u);
        b2 += __uint_as_float(u7.y << 16); b3 += __uint_as_float(u7.y & 0xffff0000u);
    }

    // self term (+I), compensated for the (n8-n) self pads already summed
    uint2 us = *(const uint2*)(lbase + (size_t)i * 128);
    const float coeff = (float)(1 - (n8 - n));
    a0 += coeff * __uint_as_float(us.x << 16);
    a1 += coeff * __uint_as_float(us.x & 0xffff0000u);
    a2 += coeff * __uint_as_float(us.y << 16);
    a3 += coeff * __uint_as_float(us.y & 0xffff0000u);

    const float dv = dinv[i];
    a0 = (a0 + b0) * dv; a1 = (a1 + b1) * dv;
    a2 = (a2 + b2) * dv; a3 = (a3 + b3) * dv;
    uint2 r;
    r.x = (uint32)f2bf(a0) | ((uint32)f2bf(a1) << 16);
    r.y = (uint32)f2bf(a2) | ((uint32)f2bf(a3) << 16);
    *(uint2*)(yw + (size_t)i * 128 + lane * 2) = r;
}

// ---------------------------------------------------------------------------
// Kernel 4: MFMA bf16 linear layer. C = relu(Y @ W^T + b) + epilogues:
//   h_out (fp32), hs_out (bf16 = dinv*(v+skip)), sum_out (fp32 = v+add_src).
// Layouts (m89/m91-verified): A[m=lane&15][k=quad*8+j]; C/D row=quad*4+reg,
// col=lane&15.
__global__ __launch_bounds__(256) void k_gemm(const unsigned short* __restrict__ Y,
                                              const unsigned short* __restrict__ W,
                                              const float* __restrict__ bias,
                                              const float* __restrict__ dinv,
                                              const float* __restrict__ skip,
                                              float* __restrict__ h_out,
                                              unsigned short* __restrict__ hs_out,
                                              float* __restrict__ sum_out,
                                              const float* __restrict__ add_src)
{
    const int tid  = threadIdx.x;
    const int w    = tid >> 6;         // wave 0..3
    const int lane = tid & 63;
    const int quad = lane >> 4;
    const int l16  = lane & 15;
    const int m0 = blockIdx.x * 64 + w * 16;   // wave's 16 rows
    const int n0 = blockIdx.y * 64;            // block's 64 cols

    frag_cd acc0 = {0.f,0.f,0.f,0.f}, acc1 = {0.f,0.f,0.f,0.f};
    frag_cd acc2 = {0.f,0.f,0.f,0.f}, acc3 = {0.f,0.f,0.f,0.f};

    const size_t abase  = (size_t)(m0 + l16) * GD + quad * 8;
    const size_t bbase0 = (size_t)(n0 +  0 + l16) * GD + quad * 8;
    const size_t bbase1 = (size_t)(n0 + 16 + l16) * GD + quad * 8;
    const size_t bbase2 = (size_t)(n0 + 32 + l16) * GD + quad * 8;
    const size_t bbase3 = (size_t)(n0 + 48 + l16) * GD + quad * 8;

#pragma unroll
    for (int k0 = 0; k0 < GD; k0 += 32) {
        frag_ab a  = *(const frag_ab*)(Y + abase  + k0);
        frag_ab b0 = *(const frag_ab*)(W + bbase0 + k0);
        frag_ab b1 = *(const frag_ab*)(W + bbase1 + k0);
        frag_ab b2 = *(const frag_ab*)(W + bbase2 + k0);
        frag_ab b3 = *(const frag_ab*)(W + bbase3 + k0);
        acc0 = __builtin_amdgcn_mfma_f32_16x16x32_bf16(a, b0, acc0, 0, 0, 0);
        acc1 = __builtin_amdgcn_mfma_f32_16x16x32_bf16(a, b1, acc1, 0, 0, 0);
        acc2 = __builtin_amdgcn_mfma_f32_16x16x32_bf16(a, b2, acc2, 0, 0, 0);
        acc3 = __builtin_amdgcn_mfma_f32_16x16x32_bf16(a, b3, acc3, 0, 0, 0);
    }

    const float bn0 = bias[n0 +  0 + l16];
    const float bn1 = bias[n0 + 16 + l16];
    const float bn2 = bias[n0 + 32 + l16];
    const float bn3 = bias[n0 + 48 + l16];

#pragma unroll
    for (int reg = 0; reg < 4; ++reg) {
        const int m = m0 + quad * 4 + reg;
        const float dv = dinv[m];
        float v[4];
        v[0] = fmaxf(acc0[reg] + bn0, 0.f);
        v[1] = fmaxf(acc1[reg] + bn1, 0.f);
        v[2] = fmaxf(acc2[reg] + bn2, 0.f);
        v[3] = fmaxf(acc3[reg] + bn3, 0.f);
#pragma unroll
        for (int nt = 0; nt < 4; ++nt) {
            const size_t idx = (size_t)m * GD + n0 + nt * 16 + l16;
            const float x = v[nt];
            if (h_out)  h_out[idx] = x;
            if (hs_out) {
                float s = skip ? skip[idx] : 0.f;
                hs_out[idx] = f2bf(dv * (x + s));
            }
            if (sum_out) sum_out[idx] = x + add_src[idx];
        }
    }
}

// ---------------------------------------------------------------------------
extern "C" void kernel_launch(void* const* d_in, const int* in_sizes, int n_in,
                              void* d_out, int out_size, void* d_ws, size_t ws_size,
                              hipStream_t stream)
{
    const float* g  = (const float*)d_in[0];
    const float* h  = (const float*)d_in[1];
    const float* Wd = (const float*)d_in[2];
    const float* bd = (const float*)d_in[3];
    const float* Wb = (const float*)d_in[4];
    const float* bb = (const float*)d_in[5];
    const float* Wu = (const float*)d_in[6];
    const float* bu = (const float*)d_in[7];
    float* out = (float*)d_out;

    char* ws = (char*)d_ws;
    float*          dinv = (float*)ws;                               // 32 KB
    int*            cnt  = (int*)(ws + 32 * 1024);                   // 32 KB
    unsigned short* col  = (unsigned short*)(ws + 64 * 1024);        // 5.24 MB
    size_t off = 64 * 1024 + (size_t)GN * CAP * sizeof(unsigned short);
    off = (off + 255) & ~(size_t)255;
    unsigned short* hs_bf = (unsigned short*)(ws + off); off += (size_t)GN * GD * 2;  // 4 MB
    unsigned short* y_bf  = (unsigned short*)(ws + off); off += (size_t)GN * GD * 2;  // 4 MB
    unsigned short* w_bf  = (unsigned short*)(ws + off); off += (size_t)7 * GD * GD * 2; // 0.9 MB
    off = (off + 255) & ~(size_t)255;
    float* dbuf1 = (float*)(ws + off); off += (size_t)GN * GD * 4;   // 8 MB
    float* dbuf2 = (float*)(ws + off); off += (size_t)GN * GD * 4;   // 8 MB
    float* dbuf3 = (float*)(ws + off); off += (size_t)GN * GD * 4;   // 8 MB
    (void)ws_size; (void)in_sizes; (void)n_in; (void)out_size;

    const size_t ND = (size_t)GN * GD;
    const int WSZ = GD * GD;   // 65536 elements per weight matrix
    dim3 ggrid(GN / 64, GD / 64);
    dim3 sgrid(GN / 4);        // 4 rows per block, one wave each

    k_build<<<GN, 256, 0, stream>>>(g, col, cnt, dinv);
    k_scale<<<GN * GD / 4 / 256, 256, 0, stream>>>(h, dinv, hs_bf);
    k_f2bf<<<3 * WSZ / 4 / 256, 256, 0, stream>>>(Wd, w_bf + 0 * (size_t)WSZ);
    k_f2bf<<<1 * WSZ / 4 / 256, 256, 0, stream>>>(Wb, w_bf + 3 * (size_t)WSZ);
    k_f2bf<<<3 * WSZ / 4 / 256, 256, 0, stream>>>(Wu, w_bf + 4 * (size_t)WSZ);

    // down 0..2: h_out -> dbuf, hs_out -> hs_bf (no skip)
    k_spmm<<<sgrid, 256, 0, stream>>>((const uint32*)hs_bf, col, cnt, dinv, (uint32*)y_bf);
    k_gemm<<<ggrid, 256, 0, stream>>>(y_bf, w_bf + 0 * (size_t)WSZ, bd + 0 * GD, dinv, nullptr, dbuf1, hs_bf, nullptr, nullptr);
    k_spmm<<<sgrid, 256, 0, stream>>>((const uint32*)hs_bf, col, cnt, dinv, (uint32*)y_bf);
    k_gemm<<<ggrid, 256, 0, stream>>>(y_bf, w_bf + 1 * (size_t)WSZ, bd + 1 * GD, dinv, nullptr, dbuf2, hs_bf, nullptr, nullptr);
    k_spmm<<<sgrid, 256, 0, stream>>>((const uint32*)hs_bf, col, cnt, dinv, (uint32*)y_bf);
    k_gemm<<<ggrid, 256, 0, stream>>>(y_bf, w_bf + 2 * (size_t)WSZ, bd + 2 * GD, dinv, nullptr, dbuf3, hs_bf, nullptr, nullptr);

    // bottom: hs_out with skip = down_outs[2]
    k_spmm<<<sgrid, 256, 0, stream>>>((const uint32*)hs_bf, col, cnt, dinv, (uint32*)y_bf);
    k_gemm<<<ggrid, 256, 0, stream>>>(y_bf, w_bf + 3 * (size_t)WSZ, bb, dinv, dbuf3, nullptr, hs_bf, nullptr, nullptr);

    // up 0: out[0] = h5; next hs with skip = down_outs[1]
    k_spmm<<<sgrid, 256, 0, stream>>>((const uint32*)hs_bf, col, cnt, dinv, (uint32*)y_bf);
    k_gemm<<<ggrid, 256, 0, stream>>>(y_bf, w_bf + 4 * (size_t)WSZ, bu + 0 * GD, dinv, dbuf2, out + 0 * ND, hs_bf, nullptr, nullptr);
    // up 1: out[1] = h6; next hs with skip = down_outs[0]
    k_spmm<<<sgrid, 256, 0, stream>>>((const uint32*)hs_bf, col, cnt, dinv, (uint32*)y_bf);
    k_gemm<<<ggrid, 256, 0, stream>>>(y_bf, w_bf + 5 * (size_t)WSZ, bu + 1 * GD, dinv, dbuf1, out + 1 * ND, hs_bf, nullptr, nullptr);
    // up 2: out[2] = h7; out[3] = h7 + org_h
    k_spmm<<<sgrid, 256, 0, stream>>>((const uint32*)hs_bf, col, cnt, dinv, (uint32*)y_bf);
    k_gemm<<<ggrid, 256, 0, stream>>>(y_bf, w_bf + 6 * (size_t)WSZ, bu + 2 * GD, dinv, nullptr, out + 2 * ND, nullptr, out + 3 * ND, h);
}

// Round 7
// 768.478 us; speedup vs baseline: 1.0564x; 1.0219x over previous
//
#include <hip/hip_runtime.h>
#include <cstdint>
#include <cstddef>

// Graph U-Net (no pooling), N=8192, D=256, L=3.
// R7: fused layer kernel. Each block: (1) aggregate 16 rows with R4-style
// gathers (LDS-staged ushort indices, per-lane uint2 = 512B/row/inst,
// unroll-8, fp32 accum), y -> LDS bf16 A-tile; (2) barrier; (3) MFMA
// 16x256 tile from LDS A-frags + global W B-frags; (4) fused epilogue
// (bias+relu+skip+dinv prescale / final sums). Removes per-layer y
// round-trip, 7 dispatch boundaries, and overlaps gather with MFMA across
// blocks. hs ping-pongs between two bf16 buffers.

#define GN 8192
#define GD 256
#define CAP 320   // max degree capacity; max observed degree ~175

typedef unsigned int uint32;
using frag_ab = __attribute__((ext_vector_type(8))) short;   // 8 bf16
using frag_cd = __attribute__((ext_vector_type(4))) float;   // 4 fp32

// RNE float -> bf16 bits (values finite)
static __device__ inline unsigned short f2bf(float x) {
    uint32 u = __float_as_uint(x);
    u += 0x7fffu + ((u >> 16) & 1u);
    return (unsigned short)(u >> 16);
}
static __device__ inline uint32 pack2bf(float lo, float hi) {
    return (uint32)f2bf(lo) | ((uint32)f2bf(hi) << 16);
}

// ---------------------------------------------------------------------------
// Kernel 1: build adjacency lists + dinv. One block per row. (R4 version)
__global__ __launch_bounds__(256) void k_build(const float* __restrict__ g,
                                               unsigned short* __restrict__ col,
                                               int* __restrict__ cnt,
                                               float* __restrict__ dinv)
{
    __shared__ int s_cnt;
    const int i = blockIdx.x;
    const int tid = threadIdx.x;
    if (tid == 0) s_cnt = 0;
    __syncthreads();
    const float4* grow = (const float4*)(g + (size_t)i * GN);
    unsigned short* crow = col + (size_t)i * CAP;
    for (int j4 = tid; j4 < GN / 4; j4 += 256) {
        float4 v = grow[j4];
        int j = j4 * 4;
        if (v.x != 0.0f) { int p = atomicAdd(&s_cnt, 1); if (p < CAP) crow[p] = (unsigned short)(j + 0); }
        if (v.y != 0.0f) { int p = atomicAdd(&s_cnt, 1); if (p < CAP) crow[p] = (unsigned short)(j + 1); }
        if (v.z != 0.0f) { int p = atomicAdd(&s_cnt, 1); if (p < CAP) crow[p] = (unsigned short)(j + 2); }
        if (v.w != 0.0f) { int p = atomicAdd(&s_cnt, 1); if (p < CAP) crow[p] = (unsigned short)(j + 3); }
    }
    __syncthreads();
    if (tid == 0) {
        int n = s_cnt; if (n > CAP) n = CAP;
        cnt[i] = n;
        dinv[i] = rsqrtf((float)s_cnt + 1.0f);
    }
}

// ---------------------------------------------------------------------------
// Kernel 2: hs_bf = bf16(dinv[:,None] * h)
__global__ __launch_bounds__(256) void k_scale(const float* __restrict__ h,
                                               const float* __restrict__ dinv,
                                               unsigned short* __restrict__ hs_bf)
{
    int idx = blockIdx.x * 256 + threadIdx.x;      // float4 index
    float4 v = ((const float4*)h)[idx];
    int row = idx / (GD / 4);
    float dv = dinv[row];
    ushort4 r;
    r.x = f2bf(v.x * dv); r.y = f2bf(v.y * dv);
    r.z = f2bf(v.z * dv); r.w = f2bf(v.w * dv);
    ((ushort4*)hs_bf)[idx] = r;
}

// ---------------------------------------------------------------------------
// Kernel 2b: generic fp32 -> bf16 convert (weights)
__global__ __launch_bounds__(256) void k_f2bf(const float* __restrict__ src,
                                              unsigned short* __restrict__ dst)
{
    int idx = blockIdx.x * 256 + threadIdx.x;      // float4 index
    float4 v = ((const float4*)src)[idx];
    ushort4 r;
    r.x = f2bf(v.x); r.y = f2bf(v.y); r.z = f2bf(v.z); r.w = f2bf(v.w);
    ((ushort4*)dst)[idx] = r;
}

// ---------------------------------------------------------------------------
// Kernel 3: fused GCN layer.
// Block = 256 threads (4 waves), 16 rows. Phase 1: wave w aggregates rows
// w*4..w*4+3 (lane owns 8B of the 512B bf16 row; indices from LDS, wave-
// coherent staging, no barrier; unroll 8 => 8 gathers in flight). y tile
// stored bf16 in LDS [16][264] (pad 8 => phase-2 ds_read_b128 2-way = free).
// Phase 2: wave w computes cols w*64..w*64+63 for all 16 rows via MFMA
// 16x16x32 (A from LDS, B=W rows from global), then fused epilogue:
//   h_out (fp32), hs_out (bf16 = dinv*(v+skip)), sum_out (fp32 = v+add_src).
__global__ __launch_bounds__(256) void k_layer(const uint32* __restrict__ hs_in,
                                               const unsigned short* __restrict__ col,
                                               const int* __restrict__ cnt,
                                               const float* __restrict__ dinv,
                                               const unsigned short* __restrict__ W,
                                               const float* __restrict__ bias,
                                               const float* __restrict__ skip,
                                               float* __restrict__ h_out,
                                               unsigned short* __restrict__ hs_out,
                                               float* __restrict__ sum_out,
                                               const float* __restrict__ add_src)
{
    __shared__ unsigned short s_idx[16][CAP];   // 10.0 KB
    __shared__ unsigned short s_y[16][264];     // 8.25 KB (8-ushort pad)
    const int tid  = threadIdx.x;
    const int w    = tid >> 6;
    const int lane = tid & 63;
    const int m0   = blockIdx.x * 16;

    // ---- Phase 1: aggregation (wave-private rows; no cross-wave deps) ----
    const uint32* lbase = hs_in + lane * 2;
#pragma unroll 1
    for (int rr = 0; rr < 4; ++rr) {
        const int lrow = w * 4 + rr;
        const int i = m0 + lrow;
        const int n = cnt[i];
        unsigned short* si = s_idx[lrow];
        for (int t = lane; t < n; t += 64) si[t] = col[(size_t)i * CAP + t];
        // wave-coherent LDS staging: producer == consumer wave.

        float a0=0.f,a1=0.f,a2=0.f,a3=0.f;      // bank A
        float b0=0.f,b1=0.f,b2=0.f,b3=0.f;      // bank B
        int t = 0;
        for (; t + 8 <= n; t += 8) {
            int c0=si[t],c1=si[t+1],c2=si[t+2],c3=si[t+3];
            int c4=si[t+4],c5=si[t+5],c6=si[t+6],c7=si[t+7];
            uint2 u0 = *(const uint2*)(lbase + (size_t)c0 * 128);
            uint2 u1 = *(const uint2*)(lbase + (size_t)c1 * 128);
            uint2 u2 = *(const uint2*)(lbase + (size_t)c2 * 128);
            uint2 u3 = *(const uint2*)(lbase + (size_t)c3 * 128);
            uint2 u4 = *(const uint2*)(lbase + (size_t)c4 * 128);
            uint2 u5 = *(const uint2*)(lbase + (size_t)c5 * 128);
            uint2 u6 = *(const uint2*)(lbase + (size_t)c6 * 128);
            uint2 u7 = *(const uint2*)(lbase + (size_t)c7 * 128);
            a0 += __uint_as_float(u0.x << 16); a1 += __uint_as_float(u0.x & 0xffff0000u);
            a2 += __uint_as_float(u0.y << 16); a3 += __uint_as_float(u0.y & 0xffff0000u);
            b0 += __uint_as_float(u1.x << 16); b1 += __uint_as_float(u1.x & 0xffff0000u);
            b2 += __uint_as_float(u1.y << 16); b3 += __uint_as_float(u1.y & 0xffff0000u);
            a0 += __uint_as_float(u2.x << 16); a1 += __uint_as_float(u2.x & 0xffff0000u);
            a2 += __uint_as_float(u2.y << 16); a3 += __uint_as_float(u2.y & 0xffff0000u);
            b0 += __uint_as_float(u3.x << 16); b1 += __uint_as_float(u3.x & 0xffff0000u);
            b2 += __uint_as_float(u3.y << 16); b3 += __uint_as_float(u3.y & 0xffff0000u);
            a0 += __uint_as_float(u4.x << 16); a1 += __uint_as_float(u4.x & 0xffff0000u);
            a2 += __uint_as_float(u4.y << 16); a3 += __uint_as_float(u4.y & 0xffff0000u);
            b0 += __uint_as_float(u5.x << 16); b1 += __uint_as_float(u5.x & 0xffff0000u);
            b2 += __uint_as_float(u5.y << 16); b3 += __uint_as_float(u5.y & 0xffff0000u);
            a0 += __uint_as_float(u6.x << 16); a1 += __uint_as_float(u6.x & 0xffff0000u);
            a2 += __uint_as_float(u6.y << 16); a3 += __uint_as_float(u6.y & 0xffff0000u);
            b0 += __uint_as_float(u7.x << 16); b1 += __uint_as_float(u7.x & 0xffff0000u);
            b2 += __uint_as_float(u7.y << 16); b3 += __uint_as_float(u7.y & 0xffff0000u);
        }
        for (; t < n; ++t) {
            uint2 u = *(const uint2*)(lbase + (size_t)si[t] * 128);
            a0 += __uint_as_float(u.x << 16); a1 += __uint_as_float(u.x & 0xffff0000u);
            a2 += __uint_as_float(u.y << 16); a3 += __uint_as_float(u.y & 0xffff0000u);
        }
        uint2 us = *(const uint2*)(lbase + (size_t)i * 128);   // self (+I)
        a0 += __uint_as_float(us.x << 16); a1 += __uint_as_float(us.x & 0xffff0000u);
        a2 += __uint_as_float(us.y << 16); a3 += __uint_as_float(us.y & 0xffff0000u);
        const float dv = dinv[i];
        a0 = (a0 + b0) * dv; a1 = (a1 + b1) * dv;
        a2 = (a2 + b2) * dv; a3 = (a3 + b3) * dv;
        uint32* yrow = (uint32*)s_y[lrow];
        yrow[lane * 2 + 0] = pack2bf(a0, a1);
        yrow[lane * 2 + 1] = pack2bf(a2, a3);
    }
    __syncthreads();

    // ---- Phase 2: MFMA 16 rows x 64 cols (cols w*64..) ----
    const int quad = lane >> 4;
    const int l16  = lane & 15;
    const int n0   = w * 64;

    frag_cd acc0 = {0.f,0.f,0.f,0.f}, acc1 = {0.f,0.f,0.f,0.f};
    frag_cd acc2 = {0.f,0.f,0.f,0.f}, acc3 = {0.f,0.f,0.f,0.f};

    const size_t bbase0 = (size_t)(n0 +  0 + l16) * GD + quad * 8;
    const size_t bbase1 = (size_t)(n0 + 16 + l16) * GD + quad * 8;
    const size_t bbase2 = (size_t)(n0 + 32 + l16) * GD + quad * 8;
    const size_t bbase3 = (size_t)(n0 + 48 + l16) * GD + quad * 8;

#pragma unroll
    for (int k0 = 0; k0 < GD; k0 += 32) {
        frag_ab a  = *(const frag_ab*)&s_y[l16][quad * 8 + k0];
        frag_ab b0 = *(const frag_ab*)(W + bbase0 + k0);
        frag_ab b1 = *(const frag_ab*)(W + bbase1 + k0);
        frag_ab b2 = *(const frag_ab*)(W + bbase2 + k0);
        frag_ab b3 = *(const frag_ab*)(W + bbase3 + k0);
        acc0 = __builtin_amdgcn_mfma_f32_16x16x32_bf16(a, b0, acc0, 0, 0, 0);
        acc1 = __builtin_amdgcn_mfma_f32_16x16x32_bf16(a, b1, acc1, 0, 0, 0);
        acc2 = __builtin_amdgcn_mfma_f32_16x16x32_bf16(a, b2, acc2, 0, 0, 0);
        acc3 = __builtin_amdgcn_mfma_f32_16x16x32_bf16(a, b3, acc3, 0, 0, 0);
    }

    const float bn0 = bias[n0 +  0 + l16];
    const float bn1 = bias[n0 + 16 + l16];
    const float bn2 = bias[n0 + 32 + l16];
    const float bn3 = bias[n0 + 48 + l16];

#pragma unroll
    for (int reg = 0; reg < 4; ++reg) {
        const int m = m0 + quad * 4 + reg;
        const float dv = dinv[m];
        float v[4];
        v[0] = fmaxf(acc0[reg] + bn0, 0.f);
        v[1] = fmaxf(acc1[reg] + bn1, 0.f);
        v[2] = fmaxf(acc2[reg] + bn2, 0.f);
        v[3] = fmaxf(acc3[reg] + bn3, 0.f);
#pragma unroll
        for (int nt = 0; nt < 4; ++nt) {
            const size_t idx = (size_t)m * GD + n0 + nt * 16 + l16;
            const float x = v[nt];
            if (h_out)  h_out[idx] = x;
            if (hs_out) {
                float s = skip ? skip[idx] : 0.f;
                hs_out[idx] = f2bf(dv * (x + s));
            }
            if (sum_out) sum_out[idx] = x + add_src[idx];
        }
    }
}

// ---------------------------------------------------------------------------
extern "C" void kernel_launch(void* const* d_in, const int* in_sizes, int n_in,
                              void* d_out, int out_size, void* d_ws, size_t ws_size,
                              hipStream_t stream)
{
    const float* g  = (const float*)d_in[0];
    const float* h  = (const float*)d_in[1];
    const float* Wd = (const float*)d_in[2];
    const float* bd = (const float*)d_in[3];
    const float* Wb = (const float*)d_in[4];
    const float* bb = (const float*)d_in[5];
    const float* Wu = (const float*)d_in[6];
    const float* bu = (const float*)d_in[7];
    float* out = (float*)d_out;

    char* ws = (char*)d_ws;
    float*          dinv = (float*)ws;                               // 32 KB
    int*            cnt  = (int*)(ws + 32 * 1024);                   // 32 KB
    unsigned short* col  = (unsigned short*)(ws + 64 * 1024);        // 5.24 MB
    size_t off = 64 * 1024 + (size_t)GN * CAP * sizeof(unsigned short);
    off = (off + 255) & ~(size_t)255;
    unsigned short* hs_a = (unsigned short*)(ws + off); off += (size_t)GN * GD * 2;  // 4 MB
    unsigned short* hs_b = (unsigned short*)(ws + off); off += (size_t)GN * GD * 2;  // 4 MB
    unsigned short* w_bf = (unsigned short*)(ws + off); off += (size_t)7 * GD * GD * 2; // 0.9 MB
    off = (off + 255) & ~(size_t)255;
    float* dbuf1 = (float*)(ws + off); off += (size_t)GN * GD * 4;   // 8 MB
    float* dbuf2 = (float*)(ws + off); off += (size_t)GN * GD * 4;   // 8 MB
    float* dbuf3 = (float*)(ws + off); off += (size_t)GN * GD * 4;   // 8 MB
    (void)ws_size; (void)in_sizes; (void)n_in; (void)out_size;

    const size_t ND = (size_t)GN * GD;
    const int WSZ = GD * GD;   // 65536 elements per weight matrix
    dim3 lgrid(GN / 16);       // 512 blocks, 16 rows each

    k_build<<<GN, 256, 0, stream>>>(g, col, cnt, dinv);
    k_scale<<<GN * GD / 4 / 256, 256, 0, stream>>>(h, dinv, hs_a);
    k_f2bf<<<3 * WSZ / 4 / 256, 256, 0, stream>>>(Wd, w_bf + 0 * (size_t)WSZ);
    k_f2bf<<<1 * WSZ / 4 / 256, 256, 0, stream>>>(Wb, w_bf + 3 * (size_t)WSZ);
    k_f2bf<<<3 * WSZ / 4 / 256, 256, 0, stream>>>(Wu, w_bf + 4 * (size_t)WSZ);

    // down 1..3
    k_layer<<<lgrid, 256, 0, stream>>>((const uint32*)hs_a, col, cnt, dinv,
        w_bf + 0 * (size_t)WSZ, bd + 0 * GD, nullptr, dbuf1, hs_b, nullptr, nullptr);
    k_layer<<<lgrid, 256, 0, stream>>>((const uint32*)hs_b, col, cnt, dinv,
        w_bf + 1 * (size_t)WSZ, bd + 1 * GD, nullptr, dbuf2, hs_a, nullptr, nullptr);
    k_layer<<<lgrid, 256, 0, stream>>>((const uint32*)hs_a, col, cnt, dinv,
        w_bf + 2 * (size_t)WSZ, bd + 2 * GD, nullptr, dbuf3, hs_b, nullptr, nullptr);
    // bottom (skip = down_outs[2])
    k_layer<<<lgrid, 256, 0, stream>>>((const uint32*)hs_b, col, cnt, dinv,
        w_bf + 3 * (size_t)WSZ, bb, dbuf3, nullptr, hs_a, nullptr, nullptr);
    // up 1: out[0]; skip = down_outs[1]
    k_layer<<<lgrid, 256, 0, stream>>>((const uint32*)hs_a, col, cnt, dinv,
        w_bf + 4 * (size_t)WSZ, bu + 0 * GD, dbuf2, out + 0 * ND, hs_b, nullptr, nullptr);
    // up 2: out[1]; skip = down_outs[0]
    k_layer<<<lgrid, 256, 0, stream>>>((const uint32*)hs_b, col, cnt, dinv,
        w_bf + 5 * (size_t)WSZ, bu + 1 * GD, dbuf1, out + 1 * ND, hs_a, nullptr, nullptr);
    // up 3: out[2]; out[3] = h7 + org_h
    k_layer<<<lgrid, 256, 0, stream>>>((const uint32*)hs_a, col, cnt, dinv,
        w_bf + 6 * (size_t)WSZ, bu + 2 * GD, nullptr, out + 2 * ND, nullptr, out + 3 * ND, h);
}

// Round 9
// 709.637 us; speedup vs baseline: 1.1440x; 1.0829x over previous
//
#include <hip/hip_runtime.h>
#include <cstdint>
#include <cstddef>

// Graph U-Net (no pooling), N=8192, D=256, L=3.
// R8b = R4 (best: 699 us) + non-temporal hints on all streaming accesses.
// (R8 failed to compile: __builtin_nontemporal_load rejects HIP float4 class;
//  use clang ext_vector float4 instead.)
// Theory: hs_bf (4 MB) fits per-XCD L2 and is re-read ~16x per XCD, but the
// col index stream + y writes + fp32 epilogue streams evict it -> gathers hit
// L3 (~600 cyc) instead of L2 (~250 cyc). SpMM is latency*concurrency bound,
// so NT-protecting hs residency should cut SpMM ~2x.

#define GN 8192
#define GD 256
#define CAP 320   // max degree capacity; max observed degree ~175

typedef unsigned int uint32;
using frag_ab = __attribute__((ext_vector_type(8))) short;   // 8 bf16
using frag_cd = __attribute__((ext_vector_type(4))) float;   // 4 fp32
using fx4     = __attribute__((ext_vector_type(4))) float;   // NT-loadable f32x4

// RNE float -> bf16 bits (values finite)
static __device__ inline unsigned short f2bf(float x) {
    uint32 u = __float_as_uint(x);
    u += 0x7fffu + ((u >> 16) & 1u);
    return (unsigned short)(u >> 16);
}

// ---------------------------------------------------------------------------
// Kernel 1: build adjacency lists + dinv. One block per row.
// g is a 256 MB one-shot stream -> NT loads.
__global__ __launch_bounds__(256) void k_build(const float* __restrict__ g,
                                               unsigned short* __restrict__ col,
                                               int* __restrict__ cnt,
                                               float* __restrict__ dinv)
{
    __shared__ int s_cnt;
    const int i = blockIdx.x;
    const int tid = threadIdx.x;
    if (tid == 0) s_cnt = 0;
    __syncthreads();
    const fx4* grow = (const fx4*)(g + (size_t)i * GN);
    unsigned short* crow = col + (size_t)i * CAP;
    for (int j4 = tid; j4 < GN / 4; j4 += 256) {
        fx4 v = __builtin_nontemporal_load(&grow[j4]);
        int j = j4 * 4;
        if (v.x != 0.0f) { int p = atomicAdd(&s_cnt, 1); if (p < CAP) crow[p] = (unsigned short)(j + 0); }
        if (v.y != 0.0f) { int p = atomicAdd(&s_cnt, 1); if (p < CAP) crow[p] = (unsigned short)(j + 1); }
        if (v.z != 0.0f) { int p = atomicAdd(&s_cnt, 1); if (p < CAP) crow[p] = (unsigned short)(j + 2); }
        if (v.w != 0.0f) { int p = atomicAdd(&s_cnt, 1); if (p < CAP) crow[p] = (unsigned short)(j + 3); }
    }
    __syncthreads();
    if (tid == 0) {
        int n = s_cnt; if (n > CAP) n = CAP;
        cnt[i] = n;
        dinv[i] = rsqrtf((float)s_cnt + 1.0f);
    }
}

// ---------------------------------------------------------------------------
// Kernel 2: hs_bf = bf16(dinv[:,None] * h)
__global__ __launch_bounds__(256) void k_scale(const float* __restrict__ h,
                                               const float* __restrict__ dinv,
                                               unsigned short* __restrict__ hs_bf)
{
    int idx = blockIdx.x * 256 + threadIdx.x;      // float4 index
    fx4 v = __builtin_nontemporal_load(&((const fx4*)h)[idx]);
    int row = idx / (GD / 4);
    float dv = dinv[row];
    ushort4 r;
    r.x = f2bf(v.x * dv); r.y = f2bf(v.y * dv);
    r.z = f2bf(v.z * dv); r.w = f2bf(v.w * dv);
    ((ushort4*)hs_bf)[idx] = r;
}

// ---------------------------------------------------------------------------
// Kernel 2b: generic fp32 -> bf16 convert (weights)
__global__ __launch_bounds__(256) void k_f2bf(const float* __restrict__ src,
                                              unsigned short* __restrict__ dst)
{
    int idx = blockIdx.x * 256 + threadIdx.x;      // float4 index
    fx4 v = __builtin_nontemporal_load(&((const fx4*)src)[idx]);
    ushort4 r;
    r.x = f2bf(v.x); r.y = f2bf(v.y); r.z = f2bf(v.z); r.w = f2bf(v.w);
    ((ushort4*)dst)[idx] = r;
}

// ---------------------------------------------------------------------------
// Kernel 3: SpMM (R4 structure). y_bf[i,:] = bf16(dinv[i]*(hs[i,:]+sum hs[c,:]))
// Grid (GN/4, 2): 4 rows/block (one wave each), 128-col chunk per blockIdx.y.
// Lane owns one uint (2 bf16); per neighbor 1 dword gather (wave = 256 B).
// NT: col staging loads (4 MB stream/dispatch), y stores (4 MB stream) ->
// keep hs_bf resident in L2.
__global__ __launch_bounds__(256) void k_spmm(const uint32* __restrict__ hsw,
                                              const unsigned short* __restrict__ col,
                                              const int* __restrict__ cnt,
                                              const float* __restrict__ dinv,
                                              uint32* __restrict__ yw)
{
    __shared__ unsigned short s_cols[4][CAP];
    const int tid = threadIdx.x;
    const int lr = tid >> 6;          // wave id = local row 0..3
    const int lane = tid & 63;
    const int i = blockIdx.x * 4 + lr;
    const int base = blockIdx.y * 64 + lane;   // uint col index (row stride 128)
    const int n = cnt[i];
    unsigned short* sc = s_cols[lr];
    for (int t = lane; t < n; t += 64)
        sc[t] = __builtin_nontemporal_load(&col[(size_t)i * CAP + t]);
    // wave-coherent staging: producer == consumer wave; no barrier.

    float alo = 0.f, ahi = 0.f;
    int t = 0;
    for (; t + 4 <= n; t += 4) {
        int c0 = sc[t], c1 = sc[t + 1], c2 = sc[t + 2], c3 = sc[t + 3];
        uint32 u0 = hsw[(size_t)c0 * 128 + base];
        uint32 u1 = hsw[(size_t)c1 * 128 + base];
        uint32 u2 = hsw[(size_t)c2 * 128 + base];
        uint32 u3 = hsw[(size_t)c3 * 128 + base];
        alo += __uint_as_float(u0 << 16); ahi += __uint_as_float(u0 & 0xffff0000u);
        alo += __uint_as_float(u1 << 16); ahi += __uint_as_float(u1 & 0xffff0000u);
        alo += __uint_as_float(u2 << 16); ahi += __uint_as_float(u2 & 0xffff0000u);
        alo += __uint_as_float(u3 << 16); ahi += __uint_as_float(u3 & 0xffff0000u);
    }
    for (; t < n; ++t) {
        uint32 u = hsw[(size_t)sc[t] * 128 + base];
        alo += __uint_as_float(u << 16); ahi += __uint_as_float(u & 0xffff0000u);
    }
    uint32 us = hsw[(size_t)i * 128 + base];   // self-loop (+I)
    alo += __uint_as_float(us << 16); ahi += __uint_as_float(us & 0xffff0000u);
    float dv = dinv[i];
    alo *= dv; ahi *= dv;
    uint32 r = (uint32)f2bf(alo) | ((uint32)f2bf(ahi) << 16);
    __builtin_nontemporal_store(r, &yw[(size_t)i * 128 + base]);
}

// ---------------------------------------------------------------------------
// Kernel 4: MFMA bf16 linear layer (R4). C = relu(Y @ W^T + b) + epilogues:
//   h_out (fp32, NT), hs_out (bf16 = dinv*(v+skip), normal — re-read heavily),
//   sum_out (fp32, NT = v+add_src). skip/add_src loads NT (one-shot streams).
// Layouts (m89/m91-verified): A[m=lane&15][k=quad*8+j]; C/D row=quad*4+reg,
// col=lane&15.
__global__ __launch_bounds__(256) void k_gemm(const unsigned short* __restrict__ Y,
                                              const unsigned short* __restrict__ W,
                                              const float* __restrict__ bias,
                                              const float* __restrict__ dinv,
                                              const float* __restrict__ skip,
                                              float* __restrict__ h_out,
                                              unsigned short* __restrict__ hs_out,
                                              float* __restrict__ sum_out,
                                              const float* __restrict__ add_src)
{
    const int tid  = threadIdx.x;
    const int w    = tid >> 6;         // wave 0..3
    const int lane = tid & 63;
    const int quad = lane >> 4;
    const int l16  = lane & 15;
    const int m0 = blockIdx.x * 64 + w * 16;   // wave's 16 rows
    const int n0 = blockIdx.y * 64;            // block's 64 cols

    frag_cd acc0 = {0.f,0.f,0.f,0.f}, acc1 = {0.f,0.f,0.f,0.f};
    frag_cd acc2 = {0.f,0.f,0.f,0.f}, acc3 = {0.f,0.f,0.f,0.f};

    const size_t abase  = (size_t)(m0 + l16) * GD + quad * 8;
    const size_t bbase0 = (size_t)(n0 +  0 + l16) * GD + quad * 8;
    const size_t bbase1 = (size_t)(n0 + 16 + l16) * GD + quad * 8;
    const size_t bbase2 = (size_t)(n0 + 32 + l16) * GD + quad * 8;
    const size_t bbase3 = (size_t)(n0 + 48 + l16) * GD + quad * 8;

#pragma unroll
    for (int k0 = 0; k0 < GD; k0 += 32) {
        frag_ab a  = *(const frag_ab*)(Y + abase  + k0);
        frag_ab b0 = *(const frag_ab*)(W + bbase0 + k0);
        frag_ab b1 = *(const frag_ab*)(W + bbase1 + k0);
        frag_ab b2 = *(const frag_ab*)(W + bbase2 + k0);
        frag_ab b3 = *(const frag_ab*)(W + bbase3 + k0);
        acc0 = __builtin_amdgcn_mfma_f32_16x16x32_bf16(a, b0, acc0, 0, 0, 0);
        acc1 = __builtin_amdgcn_mfma_f32_16x16x32_bf16(a, b1, acc1, 0, 0, 0);
        acc2 = __builtin_amdgcn_mfma_f32_16x16x32_bf16(a, b2, acc2, 0, 0, 0);
        acc3 = __builtin_amdgcn_mfma_f32_16x16x32_bf16(a, b3, acc3, 0, 0, 0);
    }

    const float bn0 = bias[n0 +  0 + l16];
    const float bn1 = bias[n0 + 16 + l16];
    const float bn2 = bias[n0 + 32 + l16];
    const float bn3 = bias[n0 + 48 + l16];

#pragma unroll
    for (int reg = 0; reg < 4; ++reg) {
        const int m = m0 + quad * 4 + reg;
        const float dv = dinv[m];
        float v[4];
        v[0] = fmaxf(acc0[reg] + bn0, 0.f);
        v[1] = fmaxf(acc1[reg] + bn1, 0.f);
        v[2] = fmaxf(acc2[reg] + bn2, 0.f);
        v[3] = fmaxf(acc3[reg] + bn3, 0.f);
#pragma unroll
        for (int nt = 0; nt < 4; ++nt) {
            const size_t idx = (size_t)m * GD + n0 + nt * 16 + l16;
            const float x = v[nt];
            if (h_out)  __builtin_nontemporal_store(x, &h_out[idx]);
            if (hs_out) {
                float s = skip ? __builtin_nontemporal_load(&skip[idx]) : 0.f;
                hs_out[idx] = f2bf(dv * (x + s));
            }
            if (sum_out) {
                float asrc = __builtin_nontemporal_load(&add_src[idx]);
                __builtin_nontemporal_store(x + asrc, &sum_out[idx]);
            }
        }
    }
}

// ---------------------------------------------------------------------------
extern "C" void kernel_launch(void* const* d_in, const int* in_sizes, int n_in,
                              void* d_out, int out_size, void* d_ws, size_t ws_size,
                              hipStream_t stream)
{
    const float* g  = (const float*)d_in[0];
    const float* h  = (const float*)d_in[1];
    const float* Wd = (const float*)d_in[2];
    const float* bd = (const float*)d_in[3];
    const float* Wb = (const float*)d_in[4];
    const float* bb = (const float*)d_in[5];
    const float* Wu = (const float*)d_in[6];
    const float* bu = (const float*)d_in[7];
    float* out = (float*)d_out;

    char* ws = (char*)d_ws;
    float*          dinv = (float*)ws;                               // 32 KB
    int*            cnt  = (int*)(ws + 32 * 1024);                   // 32 KB
    unsigned short* col  = (unsigned short*)(ws + 64 * 1024);        // 5.24 MB
    size_t off = 64 * 1024 + (size_t)GN * CAP * sizeof(unsigned short);
    off = (off + 255) & ~(size_t)255;
    unsigned short* hs_bf = (unsigned short*)(ws + off); off += (size_t)GN * GD * 2;  // 4 MB
    unsigned short* y_bf  = (unsigned short*)(ws + off); off += (size_t)GN * GD * 2;  // 4 MB
    unsigned short* w_bf  = (unsigned short*)(ws + off); off += (size_t)7 * GD * GD * 2; // 0.9 MB
    off = (off + 255) & ~(size_t)255;
    float* dbuf1 = (float*)(ws + off); off += (size_t)GN * GD * 4;   // 8 MB
    float* dbuf2 = (float*)(ws + off); off += (size_t)GN * GD * 4;   // 8 MB
    float* dbuf3 = (float*)(ws + off); off += (size_t)GN * GD * 4;   // 8 MB
    (void)ws_size; (void)in_sizes; (void)n_in; (void)out_size;

    const size_t ND = (size_t)GN * GD;
    const int WSZ = GD * GD;   // 65536 elements per weight matrix
    dim3 ggrid(GN / 64, GD / 64);
    dim3 sgrid(GN / 4, 2);

    k_build<<<GN, 256, 0, stream>>>(g, col, cnt, dinv);
    k_scale<<<GN * GD / 4 / 256, 256, 0, stream>>>(h, dinv, hs_bf);
    k_f2bf<<<3 * WSZ / 4 / 256, 256, 0, stream>>>(Wd, w_bf + 0 * (size_t)WSZ);
    k_f2bf<<<1 * WSZ / 4 / 256, 256, 0, stream>>>(Wb, w_bf + 3 * (size_t)WSZ);
    k_f2bf<<<3 * WSZ / 4 / 256, 256, 0, stream>>>(Wu, w_bf + 4 * (size_t)WSZ);

    // down 0..2: h_out -> dbuf, hs_out -> hs_bf (no skip)
    k_spmm<<<sgrid, 256, 0, stream>>>((const uint32*)hs_bf, col, cnt, dinv, (uint32*)y_bf);
    k_gemm<<<ggrid, 256, 0, stream>>>(y_bf, w_bf + 0 * (size_t)WSZ, bd + 0 * GD, dinv, nullptr, dbuf1, hs_bf, nullptr, nullptr);
    k_spmm<<<sgrid, 256, 0, stream>>>((const uint32*)hs_bf, col, cnt, dinv, (uint32*)y_bf);
    k_gemm<<<ggrid, 256, 0, stream>>>(y_bf, w_bf + 1 * (size_t)WSZ, bd + 1 * GD, dinv, nullptr, dbuf2, hs_bf, nullptr, nullptr);
    k_spmm<<<sgrid, 256, 0, stream>>>((const uint32*)hs_bf, col, cnt, dinv, (uint32*)y_bf);
    k_gemm<<<ggrid, 256, 0, stream>>>(y_bf, w_bf + 2 * (size_t)WSZ, bd + 2 * GD, dinv, nullptr, dbuf3, hs_bf, nullptr, nullptr);

    // bottom: hs_out with skip = down_outs[2]
    k_spmm<<<sgrid, 256, 0, stream>>>((const uint32*)hs_bf, col, cnt, dinv, (uint32*)y_bf);
    k_gemm<<<ggrid, 256, 0, stream>>>(y_bf, w_bf + 3 * (size_t)WSZ, bb, dinv, dbuf3, nullptr, hs_bf, nullptr, nullptr);

    // up 0: out[0] = h5; next hs with skip = down_outs[1]
    k_spmm<<<sgrid, 256, 0, stream>>>((const uint32*)hs_bf, col, cnt, dinv, (uint32*)y_bf);
    k_gemm<<<ggrid, 256, 0, stream>>>(y_bf, w_bf + 4 * (size_t)WSZ, bu + 0 * GD, dinv, dbuf2, out + 0 * ND, hs_bf, nullptr, nullptr);
    // up 1: out[1] = h6; next hs with skip = down_outs[0]
    k_spmm<<<sgrid, 256, 0, stream>>>((const uint32*)hs_bf, col, cnt, dinv, (uint32*)y_bf);
    k_gemm<<<ggrid, 256, 0, stream>>>(y_bf, w_bf + 5 * (size_t)WSZ, bu + 1 * GD, dinv, dbuf1, out + 1 * ND, hs_bf, nullptr, nullptr);
    // up 2: out[2] = h7; out[3] = h7 + org_h
    k_spmm<<<sgrid, 256, 0, stream>>>((const uint32*)hs_bf, col, cnt, dinv, (uint32*)y_bf);
    k_gemm<<<ggrid, 256, 0, stream>>>(y_bf, w_bf + 6 * (size_t)WSZ, bu + 2 * GD, dinv, nullptr, out + 2 * ND, nullptr, out + 3 * ND, h);
}